// Round 23
// baseline (154.725 us; speedup 1.0000x reference)
//
#include <hip/hip_runtime.h>
#include <hip/hip_bf16.h>

// Problem constants
#define B_N   4
#define CIN_  256
#define HH_   56
#define WW_   56
#define COUT_ 256
#define KK_   9
#define HW_   3136              // 56*56
#define KDIM  2304              // CIN_*KK_  (k index = kk*256 + ci)
#define NOFF  (B_N*18*HW_)      // 225792
#define NOUT  (B_N*COUT_*HW_)   // 3211264

typedef __attribute__((ext_vector_type(8))) short short8;   // 8 bf16 (4 VGPRs)
typedef __attribute__((ext_vector_type(4))) float float4v;  // MFMA accum

__device__ __forceinline__ short f2bf_bits(float v) {
    union { __hip_bfloat16 h; short s; } u;
    u.h = __float2bfloat16(v);
    return u.s;
}
__device__ __forceinline__ float bfbits2f(short s) {
    union { unsigned u; float f; } u2;
    u2.u = ((unsigned)(unsigned short)s) << 16;
    return u2.f;
}

// ---------------------------------------------------------------------------
// k_front: prep-only (r20: offset conv moved to MFMA).
//   bx [0,2304):      At[cout][k=kk*256+ci] bf16
//   bx [2304,3088):   xTb[b][pos][ci] bf16 (transposed x)
//   bx [3088,3376):   owT3[c][kk*256+ci] bf16, c in [0,32), rows 18..31 zero
// ---------------------------------------------------------------------------
#define NB_AT  2304
#define NB_XT  784
#define NB_OW3 288
__global__ __launch_bounds__(256) void k_front(const float* __restrict__ x,
                                               const float* __restrict__ wgt,
                                               const float* __restrict__ ow,
                                               short* __restrict__ At,
                                               short* __restrict__ xTb,
                                               short* __restrict__ owT3) {
    __shared__ float tile[64][65];
    int bx = blockIdx.x;
    int t = threadIdx.x;
    if (bx < NB_AT) {
        int i = bx*256 + t;                      // exactly COUT_*KDIM threads
        int o = i / KDIM; int r = i % KDIM;
        int kk = r >> 8;  int ci = r & 255;
        At[i] = f2bf_bits(wgt[(size_t)(o*CIN_ + ci)*9 + kk]);
        return;
    }
    if (bx < NB_AT + NB_XT) {
        int g = bx - NB_AT;                      // 0..783
        int b = g / 196; int r = g % 196;
        int c0 = (r / 49) * 64; int p0 = (r % 49) * 64;
        int tp = t & 63;  int tc = t >> 6;
        #pragma unroll
        for (int i = 0; i < 16; ++i) {
            int ci = tc*16 + i;
            tile[ci][tp] = x[((size_t)b*CIN_ + c0 + ci)*HW_ + p0 + tp];
        }
        __syncthreads();
        #pragma unroll
        for (int i = 0; i < 16; ++i) {
            int p = tc*16 + i;
            xTb[((size_t)b*HW_ + p0 + p)*CIN_ + c0 + tp] = f2bf_bits(tile[tp][p]);
        }
        return;
    }
    {   // owT3 role
        int i = (bx - NB_AT - NB_XT)*256 + t;    // exactly 32*KDIM threads
        int c = i / KDIM; int r = i % KDIM;
        int kk = r >> 8;  int ci = r & 255;
        owT3[i] = (c < 18) ? f2bf_bits(ow[(size_t)(c*CIN_ + ci)*9 + kk]) : 0;
    }
}

// ---------------------------------------------------------------------------
// k_offgemm: the 3x3 offset conv as MFMA GEMM (r20). M=32 (18 real c + pad),
// N=64, z=3 kk-split. B-tile = shifted rows of xTb with zero-pad masks.
// Deterministic.
// ---------------------------------------------------------------------------
__global__ __launch_bounds__(256) void k_offgemm(const short* __restrict__ owT3,
                                                 const short* __restrict__ xTb,
                                                 float* __restrict__ pOff2) {
    __shared__ short sA[32*64];      // 4 KB, swizzled
    __shared__ short sB[64*64];      // 8 KB, swizzled
    __shared__ int   sP2[3*64];      // shifted-pos index per (kk,row); -1=OOB
    int t = threadIdx.x;
    int posb = blockIdx.x * 64;
    int b    = blockIdx.y;
    int ks   = blockIdx.z;           // 0..2 : kk in [ks*3, ks*3+3)
    int kt0  = ks * 768;
    int kend = kt0 + 768;

    for (int e = t; e < 3*64; e += 256) {
        int kk = ks*3 + (e >> 6); int row = e & 63;
        int pos = posb + row;
        int h = pos / WW_, w = pos % WW_;
        int yy = h + kk/3 - 1, xx = w + kk%3 - 1;
        bool v = (yy >= 0) && (yy < HH_) && (xx >= 0) && (xx < WW_);
        sP2[e] = v ? (yy*WW_ + xx) : -1;
    }
    __syncthreads();

    int arow = t >> 3,  aq  = t & 7;          // sA staging: 1 short8 each
    int brow = t >> 2,  bqc = (t & 3) * 2;    // sB staging: 2 short8 each

    int wv = t >> 6;
    int wm = (wv >> 1) * 16;         // m-tile: 0 or 16
    int wn = (wv & 1) * 32;          // n: 0 or 32
    int lane = t & 63;
    int lm = lane & 15;
    int qd = lane >> 4;

    float4v acc[2];
    acc[0] = (float4v)(0.f); acc[1] = (float4v)(0.f);

    const short* gA = owT3 + (size_t)arow*KDIM + aq*8;
    const short* xb = xTb + (size_t)b*HW_*CIN_;

    short* wA = sA + (((arow >> 4)*8 + aq)*16 + ((arow + 2*aq) & 15))*8;
    short* wB[2];
    #pragma unroll
    for (int j = 0; j < 2; ++j) {
        int qq = bqc + j;
        wB[j] = sB + (((brow >> 4)*8 + qq)*16 + ((brow + 2*qq) & 15))*8;
    }

    short8 pa, pb[2];
    const short8 zero8 = (short8)(0);
    pa = *(const short8*)(gA + kt0);
    {
        int p2 = sP2[brow];
        #pragma unroll
        for (int j = 0; j < 2; ++j) {
            int ci0 = (kt0 & 255) + (bqc + j)*8;
            pb[j] = (p2 >= 0) ? *(const short8*)(xb + (size_t)p2*CIN_ + ci0) : zero8;
        }
    }

    for (int kt = kt0; kt < kend; kt += 64) {
        __syncthreads();                       // prev-iter LDS reads done
        *(short8*)wA = pa;
        #pragma unroll
        for (int j = 0; j < 2; ++j) *(short8*)wB[j] = pb[j];
        __syncthreads();
        int kt2 = kt + 64;
        if (kt2 < kend) {                      // prefetch next tiles
            pa = *(const short8*)(gA + kt2);
            int kkl = (kt2 >> 8) - ks*3;       // local kk 0..2
            int p2 = sP2[kkl*64 + brow];
            int cb = kt2 & 255;
            #pragma unroll
            for (int j = 0; j < 2; ++j) {
                int ci0 = cb + (bqc + j)*8;
                pb[j] = (p2 >= 0) ? *(const short8*)(xb + (size_t)p2*CIN_ + ci0) : zero8;
            }
        }
        #pragma unroll
        for (int kss = 0; kss < 2; ++kss) {
            int qe = kss*4 + qd;
            int sw = (lm + 2*qe) & 15;
            short8 af, bf[2];
            af = *(short8*)(sA + ((((wm>>4))*8 + qe)*16 + sw)*8);
            #pragma unroll
            for (int j = 0; j < 2; ++j)
                bf[j] = *(short8*)(sB + ((((wn>>4) + j)*8 + qe)*16 + sw)*8);
            #pragma unroll
            for (int j = 0; j < 2; ++j)
                acc[j] = __builtin_amdgcn_mfma_f32_16x16x32_bf16(
                             af, bf[j], acc[j], 0, 0, 0);
        }
    }

    float* pbase = pOff2 + (size_t)ks*NOFF;
    #pragma unroll
    for (int j = 0; j < 2; ++j) {
        int col = posb + wn + j*16 + lm;
        #pragma unroll
        for (int r = 0; r < 4; ++r) {
            int c = wm + qd*4 + r;
            if (c < 18)
                pbase[((size_t)(b*18 + c))*HW_ + col] = acc[j][r];
        }
    }
}

// ---------------------------------------------------------------------------
// k_gemm v12: BM=256 (whole COUT per block). Attacks BOTH diagnosed costs:
// gather duplication 2->1 (each (pos,kk) gathered once, not per m-block) and
// block count 1176->588 (half the barrier-drain generations). Per k-chunk a
// wave runs 16 MFMAs off 8 LDS reads (vs 8 off 6). LDS 46KB -> 3 blocks/CU.
// Grid 588: b = idx&3 keeps each XCD single-batch (XCD x serves b = x&3).
// All proven parts (z=3 split, single-buffer, swizzle, reg prefetch, packed
// cvt, plain stores) unchanged. If this is neutral -> revert r22, plateau.
// ---------------------------------------------------------------------------
__global__ __launch_bounds__(256) void k_gemm(const short* __restrict__ At,
                                              const short* __restrict__ xTb,
                                              const float* __restrict__ pOff2,
                                              const float* __restrict__ ob,
                                              float* __restrict__ pout) {
    __shared__ short sA[256*64];     // 32 KB, swizzled
    __shared__ short sB[64*64];      // 8 KB, swizzled
    __shared__ int4   sPI[3*64];
    __shared__ float4 sPW[3*64];
    int t = threadIdx.x;

    int idx = blockIdx.x;            // 0..587
    int b    = idx & 3;              // XCD x -> batch x&3 (single-batch L2)
    int r2   = idx >> 2;             // 0..146
    int posb = (r2 % 49) * 64;
    int ks   = r2 / 49;              // 0..2 : kk in [ks*3, ks*3+3)
    int kt0  = ks * 768;
    int kend = kt0 + 768;

    // ---- bilinear params (ob + 3 slice partials, fixed order) ----
    for (int e = t; e < 3*64; e += 256) {
        int kk = ks*3 + (e >> 6); int pl = e & 63;
        int pos = posb + pl;
        int h = pos / WW_, w = pos % WW_;
        size_t oy = (size_t)(b*18 + 2*kk    )*HW_ + pos;
        size_t ox = (size_t)(b*18 + 2*kk + 1)*HW_ + pos;
        float dy = ob[2*kk], dx = ob[2*kk + 1];
        #pragma unroll
        for (int s = 0; s < 3; ++s) {
            dy += pOff2[(size_t)s*NOFF + oy];
            dx += pOff2[(size_t)s*NOFF + ox];
        }
        float py = (float)(h - 1 + kk/3) + dy;
        float px = (float)(w - 1 + kk%3) + dx;
        float y0f = floorf(py), x0f = floorf(px);
        int y0 = (int)y0f, x0 = (int)x0f;
        float ty = py - y0f, tx = px - x0f;
        bool vy0 = (y0   >= 0) && (y0   < HH_);
        bool vy1 = (y0+1 >= 0) && (y0+1 < HH_);
        bool vx0 = (x0   >= 0) && (x0   < WW_);
        bool vx1 = (x0+1 >= 0) && (x0+1 < WW_);
        int y0c = min(max(y0,   0), HH_-1), y1c = min(max(y0+1, 0), HH_-1);
        int x0c = min(max(x0,   0), WW_-1), x1c = min(max(x0+1, 0), WW_-1);
        sPI[e] = make_int4(y0c*WW_+x0c, y0c*WW_+x1c, y1c*WW_+x0c, y1c*WW_+x1c);
        sPW[e] = make_float4((vy0 && vx0) ? (1.f-ty)*(1.f-tx) : 0.f,
                             (vy0 && vx1) ? (1.f-ty)*tx       : 0.f,
                             (vy1 && vx0) ? ty*(1.f-tx)       : 0.f,
                             (vy1 && vx1) ? ty*tx             : 0.f);
    }
    __syncthreads();

    int brow = t >> 2,  bqc = (t & 3) * 2;    // B staging: 2 chunks (32B)

    int wv = t >> 6;
    int wm = wv * 64;                // wave m offset: 0,64,128,192
    int lane = t & 63;
    int lm = lane & 15;
    int qd = lane >> 4;

    float4v acc[4][4];
    #pragma unroll
    for (int i = 0; i < 4; ++i)
        #pragma unroll
        for (int j = 0; j < 4; ++j) acc[i][j] = (float4v)(0.f);

    const short* gA = At + (size_t)t*KDIM;    // thread t stages A row t
    const short* xb = xTb + (size_t)b*HW_*CIN_;

    int wAo[8];                      // write offsets for row t, chunks 0..7
    #pragma unroll
    for (int j = 0; j < 8; ++j)
        wAo[j] = (((t >> 4)*8 + j)*16 + ((t + 2*j) & 15))*8;
    short* wB[2];
    #pragma unroll
    for (int j = 0; j < 2; ++j) {
        int qq = bqc + j;
        wB[j] = sB + (((brow >> 4)*8 + qq)*16 + ((brow + 2*qq) & 15))*8;
    }

    short8 pa[8], cg[2][4];
    float4 bwv;
    // prologue: tiles for kt = kt0 (local kk 0)
    #pragma unroll
    for (int j = 0; j < 8; ++j) pa[j] = *(const short8*)(gA + kt0 + j*8);
    {
        int4 id = sPI[brow]; bwv = sPW[brow];
        #pragma unroll
        for (int j = 0; j < 2; ++j) {
            int ci0 = (bqc + j)*8;
            cg[j][0] = *(const short8*)(xb + (size_t)id.x*CIN_ + ci0);
            cg[j][1] = *(const short8*)(xb + (size_t)id.y*CIN_ + ci0);
            cg[j][2] = *(const short8*)(xb + (size_t)id.z*CIN_ + ci0);
            cg[j][3] = *(const short8*)(xb + (size_t)id.w*CIN_ + ci0);
        }
    }

    #pragma unroll 1
    for (int kt = kt0; kt < kend; kt += 64) {
        // blend corners; packed bf16 cvt
        short8 pk[2];
        #pragma unroll
        for (int j = 0; j < 2; ++j) {
            float f[8];
            #pragma unroll
            for (int e = 0; e < 8; ++e)
                f[e] = bwv.x*bfbits2f(cg[j][0][e]) + bwv.y*bfbits2f(cg[j][1][e])
                     + bwv.z*bfbits2f(cg[j][2][e]) + bwv.w*bfbits2f(cg[j][3][e]);
            union { short8 s8; __hip_bfloat162 h2[4]; } pu;
            #pragma unroll
            for (int e2 = 0; e2 < 4; ++e2)
                pu.h2[e2] = __float22bfloat162_rn(make_float2(f[2*e2], f[2*e2+1]));
            pk[j] = pu.s8;
        }
        __syncthreads();                       // prev-iter LDS reads done
        #pragma unroll
        for (int j = 0; j < 8; ++j) *(short8*)(sA + wAo[j]) = pa[j];
        #pragma unroll
        for (int j = 0; j < 2; ++j) *(short8*)wB[j] = pk[j];
        __syncthreads();
        int kt2 = kt + 64;
        if (kt2 < kend) {                      // prefetch next tiles
            #pragma unroll
            for (int j = 0; j < 8; ++j) pa[j] = *(const short8*)(gA + kt2 + j*8);
            int kkl = (kt2 >> 8) - ks*3;       // local kk 0..2
            int4 id = sPI[kkl*64 + brow]; bwv = sPW[kkl*64 + brow];
            int cb = kt2 & 255;
            #pragma unroll
            for (int j = 0; j < 2; ++j) {
                int ci0 = cb + (bqc + j)*8;
                cg[j][0] = *(const short8*)(xb + (size_t)id.x*CIN_ + ci0);
                cg[j][1] = *(const short8*)(xb + (size_t)id.y*CIN_ + ci0);
                cg[j][2] = *(const short8*)(xb + (size_t)id.z*CIN_ + ci0);
                cg[j][3] = *(const short8*)(xb + (size_t)id.w*CIN_ + ci0);
            }
        }
        #pragma unroll
        for (int kss = 0; kss < 2; ++kss) {
            int qe = kss*4 + qd;
            int sw = (lm + 2*qe) & 15;
            short8 af[4], bf[4];
            #pragma unroll
            for (int i = 0; i < 4; ++i)
                af[i] = *(short8*)(sA + ((((wm>>4) + i)*8 + qe)*16 + sw)*8);
            #pragma unroll
            for (int j = 0; j < 4; ++j)
                bf[j] = *(short8*)(sB + (((j)*8 + qe)*16 + sw)*8);
            #pragma unroll
            for (int i = 0; i < 4; ++i)
                #pragma unroll
                for (int j = 0; j < 4; ++j)
                    acc[i][j] = __builtin_amdgcn_mfma_f32_16x16x32_bf16(
                                    af[i], bf[j], acc[i][j], 0, 0, 0);
        }
    }

    // epilogue -> per-slice partial. C/D layout col=lane&15 (n), row=qd*4+r.
    float* pbase = pout + (size_t)ks*NOUT;
    #pragma unroll
    for (int i = 0; i < 4; ++i)
        #pragma unroll
        for (int j = 0; j < 4; ++j) {
            int col = posb + j*16 + lm;
            #pragma unroll
            for (int r = 0; r < 4; ++r) {
                int m = wm + i*16 + qd*4 + r;
                pbase[((size_t)b*COUT_ + m)*HW_ + col] = acc[i][j][r];
            }
        }
}

// ---------------------------------------------------------------------------
// k_oreduce: out = p0 + p1 + p2 (fixed order, bit-exact; float4 vectorized).
// ---------------------------------------------------------------------------
__global__ __launch_bounds__(256) void k_oreduce(const float* __restrict__ pout,
                                                 float* __restrict__ out) {
    int i = blockIdx.x*256 + threadIdx.x;        // float4 index, NOUT/4 total
    if (i >= NOUT/4) return;
    float4 a = ((const float4*)pout)[i];
    float4 b = ((const float4*)(pout + NOUT))[i];
    float4 c = ((const float4*)(pout + 2*(size_t)NOUT))[i];
    float4 r;
    r.x = a.x + b.x + c.x;  r.y = a.y + b.y + c.y;
    r.z = a.z + b.z + c.z;  r.w = a.w + b.w + c.w;
    ((float4*)out)[i] = r;
}

// ---------------------------------------------------------------------------
extern "C" void kernel_launch(void* const* d_in, const int* in_sizes, int n_in,
                              void* d_out, int out_size, void* d_ws, size_t ws_size,
                              hipStream_t stream) {
    const float* x   = (const float*)d_in[0];
    const float* wgt = (const float*)d_in[1];
    const float* ow  = (const float*)d_in[2];
    const float* ob  = (const float*)d_in[3];
    float* out = (float*)d_out;

    char* ws = (char*)d_ws;
    // ws layout (16B aligned): At | xTb | owT3 | pOff2[3] | pout[3]  (~49MB)
    short* At    = (short*)ws;                       // 589824*2  =  1179648
    short* xTb   = (short*)(ws + 1179648);           // 3211264*2 =  6422528
    short* owT3  = (short*)(ws + 7602176);           // 32*2304*2 =   147456
    float* pOff2 = (float*)(ws + 7749632);           // 3*225792*4=  2709504
    float* pout  = (float*)(ws + 10459136);          // 3*12845056= 38535168

    k_front  <<<dim3(NB_AT + NB_XT + NB_OW3), 256, 0, stream>>>(x, wgt, ow, At, xTb, owT3);
    k_offgemm<<<dim3(49, 4, 3),               256, 0, stream>>>(owT3, xTb, pOff2);
    k_gemm   <<<dim3(588),                    256, 0, stream>>>(At, xTb, pOff2, ob, pout);
    k_oreduce<<<dim3(NOUT/4/256),             256, 0, stream>>>(pout, out);
}

// Round 24
// 133.063 us; speedup vs baseline: 1.1628x; 1.1628x over previous
//
#include <hip/hip_runtime.h>
#include <hip/hip_bf16.h>

// Problem constants
#define B_N   4
#define CIN_  256
#define HH_   56
#define WW_   56
#define COUT_ 256
#define KK_   9
#define HW_   3136              // 56*56
#define KDIM  2304              // CIN_*KK_  (k index = kk*256 + ci)
#define NOFF  (B_N*18*HW_)      // 225792
#define NOUT  (B_N*COUT_*HW_)   // 3211264

typedef __attribute__((ext_vector_type(8))) short short8;   // 8 bf16 (4 VGPRs)
typedef __attribute__((ext_vector_type(4))) float float4v;  // MFMA accum

__device__ __forceinline__ short f2bf_bits(float v) {
    union { __hip_bfloat16 h; short s; } u;
    u.h = __float2bfloat16(v);
    return u.s;
}
__device__ __forceinline__ float bfbits2f(short s) {
    union { unsigned u; float f; } u2;
    u2.u = ((unsigned)(unsigned short)s) << 16;
    return u2.f;
}

// ---------------------------------------------------------------------------
// k_front: prep-only (r20: offset conv moved to MFMA).
//   bx [0,2304):      At[cout][k=kk*256+ci] bf16
//   bx [2304,3088):   xTb[b][pos][ci] bf16 (transposed x)
//   bx [3088,3376):   owT3[c][kk*256+ci] bf16, c in [0,32), rows 18..31 zero
// ---------------------------------------------------------------------------
#define NB_AT  2304
#define NB_XT  784
#define NB_OW3 288
__global__ __launch_bounds__(256) void k_front(const float* __restrict__ x,
                                               const float* __restrict__ wgt,
                                               const float* __restrict__ ow,
                                               short* __restrict__ At,
                                               short* __restrict__ xTb,
                                               short* __restrict__ owT3) {
    __shared__ float tile[64][65];
    int bx = blockIdx.x;
    int t = threadIdx.x;
    if (bx < NB_AT) {
        int i = bx*256 + t;                      // exactly COUT_*KDIM threads
        int o = i / KDIM; int r = i % KDIM;
        int kk = r >> 8;  int ci = r & 255;
        At[i] = f2bf_bits(wgt[(size_t)(o*CIN_ + ci)*9 + kk]);
        return;
    }
    if (bx < NB_AT + NB_XT) {
        int g = bx - NB_AT;                      // 0..783
        int b = g / 196; int r = g % 196;
        int c0 = (r / 49) * 64; int p0 = (r % 49) * 64;
        int tp = t & 63;  int tc = t >> 6;
        #pragma unroll
        for (int i = 0; i < 16; ++i) {
            int ci = tc*16 + i;
            tile[ci][tp] = x[((size_t)b*CIN_ + c0 + ci)*HW_ + p0 + tp];
        }
        __syncthreads();
        #pragma unroll
        for (int i = 0; i < 16; ++i) {
            int p = tc*16 + i;
            xTb[((size_t)b*HW_ + p0 + p)*CIN_ + c0 + tp] = f2bf_bits(tile[tp][p]);
        }
        return;
    }
    {   // owT3 role
        int i = (bx - NB_AT - NB_XT)*256 + t;    // exactly 32*KDIM threads
        int c = i / KDIM; int r = i % KDIM;
        int kk = r >> 8;  int ci = r & 255;
        owT3[i] = (c < 18) ? f2bf_bits(ow[(size_t)(c*CIN_ + ci)*9 + kk]) : 0;
    }
}

// ---------------------------------------------------------------------------
// k_offgemm: the 3x3 offset conv as MFMA GEMM (r20). M=32 (18 real c + pad),
// N=64, z=3 kk-split. B-tile = shifted rows of xTb with zero-pad masks.
// Deterministic (fixed in-block K order, plain partial stores).
// ---------------------------------------------------------------------------
__global__ __launch_bounds__(256) void k_offgemm(const short* __restrict__ owT3,
                                                 const short* __restrict__ xTb,
                                                 float* __restrict__ pOff2) {
    __shared__ short sA[32*64];      // 4 KB, swizzled
    __shared__ short sB[64*64];      // 8 KB, swizzled
    __shared__ int   sP2[3*64];      // shifted-pos index per (kk,row); -1=OOB
    int t = threadIdx.x;
    int posb = blockIdx.x * 64;
    int b    = blockIdx.y;
    int ks   = blockIdx.z;           // 0..2 : kk in [ks*3, ks*3+3)
    int kt0  = ks * 768;
    int kend = kt0 + 768;

    for (int e = t; e < 3*64; e += 256) {
        int kk = ks*3 + (e >> 6); int row = e & 63;
        int pos = posb + row;
        int h = pos / WW_, w = pos % WW_;
        int yy = h + kk/3 - 1, xx = w + kk%3 - 1;
        bool v = (yy >= 0) && (yy < HH_) && (xx >= 0) && (xx < WW_);
        sP2[e] = v ? (yy*WW_ + xx) : -1;
    }
    __syncthreads();

    int arow = t >> 3,  aq  = t & 7;          // sA staging: 1 short8 each
    int brow = t >> 2,  bqc = (t & 3) * 2;    // sB staging: 2 short8 each

    int wv = t >> 6;
    int wm = (wv >> 1) * 16;         // m-tile: 0 or 16
    int wn = (wv & 1) * 32;          // n: 0 or 32
    int lane = t & 63;
    int lm = lane & 15;
    int qd = lane >> 4;

    float4v acc[2];
    acc[0] = (float4v)(0.f); acc[1] = (float4v)(0.f);

    const short* gA = owT3 + (size_t)arow*KDIM + aq*8;
    const short* xb = xTb + (size_t)b*HW_*CIN_;

    short* wA = sA + (((arow >> 4)*8 + aq)*16 + ((arow + 2*aq) & 15))*8;
    short* wB[2];
    #pragma unroll
    for (int j = 0; j < 2; ++j) {
        int qq = bqc + j;
        wB[j] = sB + (((brow >> 4)*8 + qq)*16 + ((brow + 2*qq) & 15))*8;
    }

    short8 pa, pb[2];
    const short8 zero8 = (short8)(0);
    pa = *(const short8*)(gA + kt0);
    {
        int p2 = sP2[brow];
        #pragma unroll
        for (int j = 0; j < 2; ++j) {
            int ci0 = (kt0 & 255) + (bqc + j)*8;
            pb[j] = (p2 >= 0) ? *(const short8*)(xb + (size_t)p2*CIN_ + ci0) : zero8;
        }
    }

    for (int kt = kt0; kt < kend; kt += 64) {
        __syncthreads();                       // prev-iter LDS reads done
        *(short8*)wA = pa;
        #pragma unroll
        for (int j = 0; j < 2; ++j) *(short8*)wB[j] = pb[j];
        __syncthreads();
        int kt2 = kt + 64;
        if (kt2 < kend) {                      // prefetch next tiles
            pa = *(const short8*)(gA + kt2);
            int kkl = (kt2 >> 8) - ks*3;       // local kk 0..2
            int p2 = sP2[kkl*64 + brow];
            int cb = kt2 & 255;
            #pragma unroll
            for (int j = 0; j < 2; ++j) {
                int ci0 = cb + (bqc + j)*8;
                pb[j] = (p2 >= 0) ? *(const short8*)(xb + (size_t)p2*CIN_ + ci0) : zero8;
            }
        }
        #pragma unroll
        for (int kss = 0; kss < 2; ++kss) {
            int qe = kss*4 + qd;
            int sw = (lm + 2*qe) & 15;
            short8 af, bf[2];
            af = *(short8*)(sA + ((((wm>>4))*8 + qe)*16 + sw)*8);
            #pragma unroll
            for (int j = 0; j < 2; ++j)
                bf[j] = *(short8*)(sB + ((((wn>>4) + j)*8 + qe)*16 + sw)*8);
            #pragma unroll
            for (int j = 0; j < 2; ++j)
                acc[j] = __builtin_amdgcn_mfma_f32_16x16x32_bf16(
                             af, bf[j], acc[j], 0, 0, 0);
        }
    }

    float* pbase = pOff2 + (size_t)ks*NOFF;
    #pragma unroll
    for (int j = 0; j < 2; ++j) {
        int col = posb + wn + j*16 + lm;
        #pragma unroll
        for (int r = 0; r < 4; ++r) {
            int c = wm + qd*4 + r;
            if (c < 18)
                pbase[((size_t)(b*18 + c))*HW_ + col] = acc[j][r];
        }
    }
}

// ---------------------------------------------------------------------------
// k_gemm: the r15/r20/r22-proven kernel (47us measured, 3x reproduced).
// BM=128/BN=64, z=3 K-split, XCD swizzle, single-buffer swizzled LDS, reg
// prefetch, packed bf16 cvt, plain pout stores. THE CO-RESIDENCY LAW (r16,
// r21, r23): this kernel is block-concurrency-bound — z=6, ping-pong dbuf,
// and BM=256 all cut blocks/CU and all regressed despite improving per-block
// metrics. NO fences/atomics (r17 fence storm). This is the structure's
// measured optimum; further gains need a ground-up wave-specialized K-loop.
// ---------------------------------------------------------------------------
__global__ __launch_bounds__(256) void k_gemm(const short* __restrict__ At,
                                              const short* __restrict__ xTb,
                                              const float* __restrict__ pOff2,
                                              const float* __restrict__ ob,
                                              float* __restrict__ pout) {
    __shared__ short sA[128*64];     // 16 KB, swizzled
    __shared__ short sB[64*64];      // 8 KB, swizzled
    __shared__ int4   sPI[3*64];
    __shared__ float4 sPW[3*64];
    int t = threadIdx.x;

    int idx = blockIdx.x;            // 0..1175
    int xcd = idx & 7;
    int b   = xcd & 3;
    int q   = (idx >> 3)*2 + (xcd >> 2);
    int m0   = (q & 1) * 128;
    int r2   = q >> 1;
    int posb = (r2 % 49) * 64;
    int ks   = r2 / 49;              // 0..2 : kk in [ks*3, ks*3+3)
    int kt0  = ks * 768;
    int kend = kt0 + 768;

    // ---- bilinear params (ob + 3 slice partials, fixed order) ----
    for (int e = t; e < 3*64; e += 256) {
        int kk = ks*3 + (e >> 6); int pl = e & 63;
        int pos = posb + pl;
        int h = pos / WW_, w = pos % WW_;
        size_t oy = (size_t)(b*18 + 2*kk    )*HW_ + pos;
        size_t ox = (size_t)(b*18 + 2*kk + 1)*HW_ + pos;
        float dy = ob[2*kk], dx = ob[2*kk + 1];
        #pragma unroll
        for (int s = 0; s < 3; ++s) {
            dy += pOff2[(size_t)s*NOFF + oy];
            dx += pOff2[(size_t)s*NOFF + ox];
        }
        float py = (float)(h - 1 + kk/3) + dy;
        float px = (float)(w - 1 + kk%3) + dx;
        float y0f = floorf(py), x0f = floorf(px);
        int y0 = (int)y0f, x0 = (int)x0f;
        float ty = py - y0f, tx = px - x0f;
        bool vy0 = (y0   >= 0) && (y0   < HH_);
        bool vy1 = (y0+1 >= 0) && (y0+1 < HH_);
        bool vx0 = (x0   >= 0) && (x0   < WW_);
        bool vx1 = (x0+1 >= 0) && (x0+1 < WW_);
        int y0c = min(max(y0,   0), HH_-1), y1c = min(max(y0+1, 0), HH_-1);
        int x0c = min(max(x0,   0), WW_-1), x1c = min(max(x0+1, 0), WW_-1);
        sPI[e] = make_int4(y0c*WW_+x0c, y0c*WW_+x1c, y1c*WW_+x0c, y1c*WW_+x1c);
        sPW[e] = make_float4((vy0 && vx0) ? (1.f-ty)*(1.f-tx) : 0.f,
                             (vy0 && vx1) ? (1.f-ty)*tx       : 0.f,
                             (vy1 && vx0) ? ty*(1.f-tx)       : 0.f,
                             (vy1 && vx1) ? ty*tx             : 0.f);
    }
    __syncthreads();

    int arow = t >> 1,  aqc = (t & 1) * 4;    // A staging: 4 chunks (64B)
    int brow = t >> 2,  bqc = (t & 3) * 2;    // B staging: 2 chunks (32B)

    int wv = t >> 6;
    int wm = (wv >> 1) * 64;
    int wn = (wv & 1) * 32;
    int lane = t & 63;
    int lm = lane & 15;
    int qd = lane >> 4;

    float4v acc[4][2];
    #pragma unroll
    for (int i = 0; i < 4; ++i)
        #pragma unroll
        for (int j = 0; j < 2; ++j) acc[i][j] = (float4v)(0.f);

    const short* gA = At + (size_t)(m0 + arow)*KDIM + aqc*8;
    const short* xb = xTb + (size_t)b*HW_*CIN_;

    short* wA[4]; short* wB[2];
    #pragma unroll
    for (int j = 0; j < 4; ++j) {
        int qq = aqc + j;
        wA[j] = sA + (((arow >> 4)*8 + qq)*16 + ((arow + 2*qq) & 15))*8;
    }
    #pragma unroll
    for (int j = 0; j < 2; ++j) {
        int qq = bqc + j;
        wB[j] = sB + (((brow >> 4)*8 + qq)*16 + ((brow + 2*qq) & 15))*8;
    }

    short8 pa[4], cg[2][4];
    float4 bwv;
    // prologue: tiles for kt = kt0 (local kk 0)
    #pragma unroll
    for (int j = 0; j < 4; ++j) pa[j] = *(const short8*)(gA + kt0 + j*8);
    {
        int4 id = sPI[brow]; bwv = sPW[brow];
        #pragma unroll
        for (int j = 0; j < 2; ++j) {
            int ci0 = (bqc + j)*8;
            cg[j][0] = *(const short8*)(xb + (size_t)id.x*CIN_ + ci0);
            cg[j][1] = *(const short8*)(xb + (size_t)id.y*CIN_ + ci0);
            cg[j][2] = *(const short8*)(xb + (size_t)id.z*CIN_ + ci0);
            cg[j][3] = *(const short8*)(xb + (size_t)id.w*CIN_ + ci0);
        }
    }

    for (int kt = kt0; kt < kend; kt += 64) {
        // blend corners; packed bf16 cvt
        short8 pk[2];
        #pragma unroll
        for (int j = 0; j < 2; ++j) {
            float f[8];
            #pragma unroll
            for (int e = 0; e < 8; ++e)
                f[e] = bwv.x*bfbits2f(cg[j][0][e]) + bwv.y*bfbits2f(cg[j][1][e])
                     + bwv.z*bfbits2f(cg[j][2][e]) + bwv.w*bfbits2f(cg[j][3][e]);
            union { short8 s8; __hip_bfloat162 h2[4]; } pu;
            #pragma unroll
            for (int e2 = 0; e2 < 4; ++e2)
                pu.h2[e2] = __float22bfloat162_rn(make_float2(f[2*e2], f[2*e2+1]));
            pk[j] = pu.s8;
        }
        __syncthreads();                       // prev-iter LDS reads done
        #pragma unroll
        for (int j = 0; j < 4; ++j) *(short8*)wA[j] = pa[j];
        #pragma unroll
        for (int j = 0; j < 2; ++j) *(short8*)wB[j] = pk[j];
        __syncthreads();
        int kt2 = kt + 64;
        if (kt2 < kend) {                      // prefetch next tiles
            #pragma unroll
            for (int j = 0; j < 4; ++j) pa[j] = *(const short8*)(gA + kt2 + j*8);
            int kkl = (kt2 >> 8) - ks*3;       // local kk 0..2
            int4 id = sPI[kkl*64 + brow]; bwv = sPW[kkl*64 + brow];
            int cb = kt2 & 255;
            #pragma unroll
            for (int j = 0; j < 2; ++j) {
                int ci0 = cb + (bqc + j)*8;
                cg[j][0] = *(const short8*)(xb + (size_t)id.x*CIN_ + ci0);
                cg[j][1] = *(const short8*)(xb + (size_t)id.y*CIN_ + ci0);
                cg[j][2] = *(const short8*)(xb + (size_t)id.z*CIN_ + ci0);
                cg[j][3] = *(const short8*)(xb + (size_t)id.w*CIN_ + ci0);
            }
        }
        #pragma unroll
        for (int kss = 0; kss < 2; ++kss) {
            int qe = kss*4 + qd;
            int sw = (lm + 2*qe) & 15;
            short8 af[4], bf[2];
            #pragma unroll
            for (int i = 0; i < 4; ++i)
                af[i] = *(short8*)(sA + ((((wm>>4) + i)*8 + qe)*16 + sw)*8);
            #pragma unroll
            for (int j = 0; j < 2; ++j)
                bf[j] = *(short8*)(sB + ((((wn>>4) + j)*8 + qe)*16 + sw)*8);
            #pragma unroll
            for (int i = 0; i < 4; ++i)
                #pragma unroll
                for (int j = 0; j < 2; ++j)
                    acc[i][j] = __builtin_amdgcn_mfma_f32_16x16x32_bf16(
                                    af[i], bf[j], acc[i][j], 0, 0, 0);
        }
    }

    // epilogue -> per-slice partial. C/D layout col=lane&15 (n), row=qd*4+r.
    float* pbase = pout + (size_t)ks*NOUT;
    #pragma unroll
    for (int i = 0; i < 4; ++i)
        #pragma unroll
        for (int j = 0; j < 2; ++j) {
            int col = posb + wn + j*16 + lm;
            #pragma unroll
            for (int r = 0; r < 4; ++r) {
                int m = m0 + wm + i*16 + qd*4 + r;
                pbase[((size_t)b*COUT_ + m)*HW_ + col] = acc[i][j][r];
            }
        }
}

// ---------------------------------------------------------------------------
// k_oreduce: out = p0 + p1 + p2 (fixed order, bit-exact; float4 vectorized).
// ---------------------------------------------------------------------------
__global__ __launch_bounds__(256) void k_oreduce(const float* __restrict__ pout,
                                                 float* __restrict__ out) {
    int i = blockIdx.x*256 + threadIdx.x;        // float4 index, NOUT/4 total
    if (i >= NOUT/4) return;
    float4 a = ((const float4*)pout)[i];
    float4 b = ((const float4*)(pout + NOUT))[i];
    float4 c = ((const float4*)(pout + 2*(size_t)NOUT))[i];
    float4 r;
    r.x = a.x + b.x + c.x;  r.y = a.y + b.y + c.y;
    r.z = a.z + b.z + c.z;  r.w = a.w + b.w + c.w;
    ((float4*)out)[i] = r;
}

// ---------------------------------------------------------------------------
extern "C" void kernel_launch(void* const* d_in, const int* in_sizes, int n_in,
                              void* d_out, int out_size, void* d_ws, size_t ws_size,
                              hipStream_t stream) {
    const float* x   = (const float*)d_in[0];
    const float* wgt = (const float*)d_in[1];
    const float* ow  = (const float*)d_in[2];
    const float* ob  = (const float*)d_in[3];
    float* out = (float*)d_out;

    char* ws = (char*)d_ws;
    // ws layout (16B aligned): At | xTb | owT3 | pOff2[3] | pout[3]  (~49MB)
    short* At    = (short*)ws;                       // 589824*2  =  1179648
    short* xTb   = (short*)(ws + 1179648);           // 3211264*2 =  6422528
    short* owT3  = (short*)(ws + 7602176);           // 32*2304*2 =   147456
    float* pOff2 = (float*)(ws + 7749632);           // 3*225792*4=  2709504
    float* pout  = (float*)(ws + 10459136);          // 3*12845056= 38535168

    k_front  <<<dim3(NB_AT + NB_XT + NB_OW3), 256, 0, stream>>>(x, wgt, ow, At, xTb, owT3);
    k_offgemm<<<dim3(49, 4, 3),               256, 0, stream>>>(owT3, xTb, pOff2);
    k_gemm   <<<dim3(1176),                   256, 0, stream>>>(At, xTb, pOff2, ob, pout);
    k_oreduce<<<dim3(NOUT/4/256),             256, 0, stream>>>(pout, out);
}